// Round 4
// baseline (492.192 us; speedup 1.0000x reference)
//
#include <hip/hip_runtime.h>

typedef unsigned short ushort_t;
typedef unsigned int uint_t;

#define L_TOK 3072
#define DMODEL 512
#define WELEM 262144   // 512*512

using bf16x8 = __attribute__((ext_vector_type(8))) short;
using f32x4  = __attribute__((ext_vector_type(4))) float;

__device__ __forceinline__ float b2f(ushort_t u) {
    union { uint_t i; float f; } c; c.i = ((uint_t)u) << 16; return c.f;
}
__device__ __forceinline__ ushort_t f2b(float f) {
    union { float f; uint_t i; } c; c.f = f;
    uint_t x = c.i;
    return (ushort_t)((x + 0x7fffu + ((x >> 16) & 1u)) >> 16);  // RNE
}

// ---------------- Weight convert: 6 matrices of 512x512 fp32 -> bf16 (RNE)
__global__ __launch_bounds__(256) void convert_weights(
    const float* __restrict__ Wq, const float* __restrict__ Wk, const float* __restrict__ Wv,
    const float* __restrict__ Wo, const float* __restrict__ W1, const float* __restrict__ W2,
    ushort_t* __restrict__ WB)
{
    int gid = blockIdx.x * 256 + threadIdx.x;     // 393216 threads, 4 floats each
    int mat = gid >> 16;                          // 65536 threads per matrix
    int off = (gid & 65535) * 4;
    const float* src;
    switch (mat) {
        case 0: src = Wq; break;
        case 1: src = Wk; break;
        case 2: src = Wv; break;
        case 3: src = Wo; break;
        case 4: src = W1; break;
        default: src = W2; break;
    }
    float4 v = *reinterpret_cast<const float4*>(src + off);
    uint2 o;
    o.x = (uint_t)f2b(v.x) | ((uint_t)f2b(v.y) << 16);
    o.y = (uint_t)f2b(v.z) | ((uint_t)f2b(v.w) << 16);
    *reinterpret_cast<uint2*>(&WB[mat * WELEM + off]) = o;
}

// ---------------- Embedding (fp32 tables -> bf16 X)
__global__ __launch_bounds__(256) void embed_kernel(
    const int* __restrict__ idx,
    const float* __restrict__ Wt, const float* __restrict__ bt,
    const float* __restrict__ Wa, const float* __restrict__ ba,
    const float* __restrict__ Wm, const float* __restrict__ bm,
    const float* __restrict__ sos, ushort_t* __restrict__ X)
{
    int gid = blockIdx.x * 256 + threadIdx.x;   // 3072*512 total
    int tok = gid >> 9;
    int d = gid & 511;
    float val;
    if (tok == 0) {
        val = sos[d];
    } else {
        int id = idx[tok - 1];
        int t = id / 219;            // 73*3
        int a = (id / 3) % 73;
        int m = id % 3;
        val = Wt[d * 15 + t] + bt[d]
            + Wa[d * 73 + a] + ba[d]
            + Wm[d * 3 + m] + bm[d];
    }
    X[gid] = f2b(val);
}

// ---------------- start[] scan (ping-pong, race-free)
__global__ __launch_bounds__(1024) void scan_start(const int* __restrict__ seq, int* __restrict__ start)
{
    __shared__ int buf0[1024];
    __shared__ int buf1[1024];
    int tid = threadIdx.x;
    int carry = 0;
    for (int c = 0; c < 3; c++) {
        int i = c * 1024 + tid;
        int b;
        if (i <= 1) b = i;
        else b = (seq[i - 1] == 0) ? i : 0;
        buf0[tid] = b;
        __syncthreads();
        int* src = buf0;
        int* dst = buf1;
        for (int off = 1; off < 1024; off <<= 1) {
            int v = src[tid];
            if (tid >= off) { int u = src[tid - off]; if (u > v) v = u; }
            dst[tid] = v;
            __syncthreads();
            int* t = src; src = dst; dst = t;
        }
        int val = src[tid] > carry ? src[tid] : carry;
        start[i] = val;
        int tot = src[1023] > carry ? src[1023] : carry;
        __syncthreads();
        carry = tot;
    }
}

// ---------------- GEMM: C[3072,512] = A@W^T + bias; A,W,C bf16, bias fp32, fp32 acc
template<int RELU>
__global__ __launch_bounds__(256) void gemm512(
    const ushort_t* __restrict__ A,
    const ushort_t* __restrict__ Wp0, const ushort_t* __restrict__ Wp1, const ushort_t* __restrict__ Wp2,
    const float* __restrict__ bp0, const float* __restrict__ bp1, const float* __restrict__ bp2,
    ushort_t* __restrict__ Cp0, ushort_t* __restrict__ Cp1, ushort_t* __restrict__ Cp2)
{
    const ushort_t* W = Wp0; const float* bias = bp0; ushort_t* C = Cp0;
    if (blockIdx.z == 1) { W = Wp1; bias = bp1; C = Cp1; }
    else if (blockIdx.z == 2) { W = Wp2; bias = bp2; C = Cp2; }

    __shared__ ushort_t As[64 * 72];
    __shared__ ushort_t Bs[64 * 72];

    const int tid = threadIdx.x;
    const int lane = tid & 63;
    const int w = tid >> 6;
    const int lm = lane & 15;
    const int q4 = lane >> 4;

    const int m0 = blockIdx.x * 64;
    const int n0 = blockIdx.y * 64;

    f32x4 acc[4];
#pragma unroll
    for (int i = 0; i < 4; i++) acc[i] = (f32x4){0.f, 0.f, 0.f, 0.f};

    for (int k0 = 0; k0 < 512; k0 += 64) {
        for (int c = tid; c < 512; c += 256) {
            int row = c >> 3, col = (c & 7) << 3;
            uint4 va = *reinterpret_cast<const uint4*>(&A[(size_t)(m0 + row) * 512 + k0 + col]);
            *reinterpret_cast<uint4*>(&As[row * 72 + col]) = va;
            uint4 vb = *reinterpret_cast<const uint4*>(&W[(size_t)(n0 + row) * 512 + k0 + col]);
            *reinterpret_cast<uint4*>(&Bs[row * 72 + col]) = vb;
        }
        __syncthreads();
#pragma unroll
        for (int kk = 0; kk < 64; kk += 32) {
            bf16x8 af = *reinterpret_cast<const bf16x8*>(&As[(w * 16 + lm) * 72 + kk + q4 * 8]);
#pragma unroll
            for (int nt = 0; nt < 4; nt++) {
                bf16x8 bf = *reinterpret_cast<const bf16x8*>(&Bs[(nt * 16 + lm) * 72 + kk + q4 * 8]);
                acc[nt] = __builtin_amdgcn_mfma_f32_16x16x32_bf16(af, bf, acc[nt], 0, 0, 0);
            }
        }
        __syncthreads();
    }

#pragma unroll
    for (int nt = 0; nt < 4; nt++) {
        int col = n0 + nt * 16 + lm;
        float bv = bias[col];
#pragma unroll
        for (int r = 0; r < 4; r++) {
            int row = m0 + w * 16 + q4 * 4 + r;
            float v = acc[nt][r] + bv;
            if (RELU) v = (v > 0.f) ? v : 0.01f * v;
            C[(size_t)row * 512 + col] = f2b(v);
        }
    }
}

// ---------------- Sparse attention: keys = {0} ∪ [start[i], i-1], one wave per (token i, head h)
__global__ __launch_bounds__(256) void attn_kernel(
    const ushort_t* __restrict__ Q, const ushort_t* __restrict__ K,
    const ushort_t* __restrict__ V, const int* __restrict__ START,
    ushort_t* __restrict__ O)
{
    int wid = blockIdx.x * 4 + (threadIdx.x >> 6);
    int lane = threadIdx.x & 63;
    int i = wid >> 3;
    int h = wid & 7;

    float qv = b2f(Q[(size_t)i * 512 + h * 64 + lane]) * 0.125f;  // fold 1/sqrt(64)
    int si = START[i];
    if (si < 1) si = 1;
    if (si > i) si = i;
    int nk = (i == 0) ? 1 : (i - si + 1);

    float m_run = -INFINITY, l_run = 0.f, o_acc = 0.f;

    for (int t0 = 0; t0 < nk; t0 += 64) {
        int t = t0 + lane;
        bool valid = t < nk;
        int j = (t == 0) ? 0 : (si + t - 1);
        if (!valid) j = 0;
        if (j < 0) j = 0; if (j > L_TOK - 1) j = L_TOK - 1;
        const uint4* kp = reinterpret_cast<const uint4*>(&K[(size_t)j * 512 + h * 64]);
        float s = 0.f;
#pragma unroll
        for (int c = 0; c < 8; c++) {
            uint4 u = kp[c];
            uint_t uu[4] = {u.x, u.y, u.z, u.w};
#pragma unroll
            for (int p2 = 0; p2 < 4; p2++) {
                int d = c * 8 + p2 * 2;
                s += __shfl(qv, d) * b2f((ushort_t)(uu[p2] & 0xffffu));
                s += __shfl(qv, d + 1) * b2f((ushort_t)(uu[p2] >> 16));
            }
        }
        if (!valid) s = -INFINITY;

        float tmax = s;
#pragma unroll
        for (int off = 32; off > 0; off >>= 1) tmax = fmaxf(tmax, __shfl_xor(tmax, off));
        float m_new = fmaxf(m_run, tmax);
        float p = valid ? __expf(s - m_new) : 0.f;
        float psum = p;
#pragma unroll
        for (int off = 32; off > 0; off >>= 1) psum += __shfl_xor(psum, off);
        float alpha = (m_run == -INFINITY) ? 0.f : __expf(m_run - m_new);
        l_run = l_run * alpha + psum;
        o_acc *= alpha;

        int lim = nk - t0; if (lim > 64) lim = 64;
        for (int t2 = 0; t2 < lim; t2++) {
            float pj = __shfl(p, t2);
            int g = t0 + t2;
            int jj = (g == 0) ? 0 : (si + g - 1);
            if (jj < 0) jj = 0; if (jj > L_TOK - 1) jj = L_TOK - 1;
            o_acc += pj * b2f(V[(size_t)jj * 512 + h * 64 + lane]);
        }
        m_run = m_new;
    }
    float inv = (l_run > 0.f) ? (1.f / l_run) : 0.f;
    O[(size_t)i * 512 + h * 64 + lane] = f2b(o_acc * inv);
}

// ---------------- LayerNorm (one wave per token); RESID adds R; F32OUT selects output format
template<int RESID, int F32OUT>
__global__ __launch_bounds__(256) void ln_kernel(
    const ushort_t* __restrict__ X, const ushort_t* __restrict__ R,
    const float* __restrict__ g, const float* __restrict__ be,
    void* __restrict__ outv)
{
    int tok = blockIdx.x * 4 + (threadIdx.x >> 6);
    int lane = threadIdx.x & 63;
    size_t base = (size_t)tok * 512 + lane * 8;

    float v[8];
    {
        uint4 ux = *reinterpret_cast<const uint4*>(&X[base]);
        uint_t ua[4] = {ux.x, ux.y, ux.z, ux.w};
#pragma unroll
        for (int p = 0; p < 4; p++) {
            v[2 * p] = b2f((ushort_t)(ua[p] & 0xffffu));
            v[2 * p + 1] = b2f((ushort_t)(ua[p] >> 16));
        }
        if (RESID) {
            uint4 ur = *reinterpret_cast<const uint4*>(&R[base]);
            uint_t ub[4] = {ur.x, ur.y, ur.z, ur.w};
#pragma unroll
            for (int p = 0; p < 4; p++) {
                v[2 * p] += b2f((ushort_t)(ub[p] & 0xffffu));
                v[2 * p + 1] += b2f((ushort_t)(ub[p] >> 16));
            }
        }
    }
    float sum = 0.f;
#pragma unroll
    for (int j = 0; j < 8; j++) sum += v[j];
#pragma unroll
    for (int off = 32; off > 0; off >>= 1) sum += __shfl_xor(sum, off);
    float mu = sum * (1.f / 512.f);
    float var = 0.f;
#pragma unroll
    for (int j = 0; j < 8; j++) { float d = v[j] - mu; var += d * d; }
#pragma unroll
    for (int off = 32; off > 0; off >>= 1) var += __shfl_xor(var, off);
    float rstd = rsqrtf(var * (1.f / 512.f) + 1e-5f);

    const float4* gp = reinterpret_cast<const float4*>(g);
    const float4* bp = reinterpret_cast<const float4*>(be);
    float4 g0 = gp[2 * lane], g1 = gp[2 * lane + 1];
    float4 b0 = bp[2 * lane], b1 = bp[2 * lane + 1];
    float gg[8] = {g0.x, g0.y, g0.z, g0.w, g1.x, g1.y, g1.z, g1.w};
    float bb[8] = {b0.x, b0.y, b0.z, b0.w, b1.x, b1.y, b1.z, b1.w};

    float o[8];
#pragma unroll
    for (int j = 0; j < 8; j++) o[j] = (v[j] - mu) * rstd * gg[j] + bb[j];

    if (F32OUT) {
        float* outf = (float*)outv;
        float4 o0 = {o[0], o[1], o[2], o[3]};
        float4 o1 = {o[4], o[5], o[6], o[7]};
        *reinterpret_cast<float4*>(&outf[base]) = o0;
        *reinterpret_cast<float4*>(&outf[base + 4]) = o1;
    } else {
        ushort_t* outb = (ushort_t*)outv;
        uint_t outp[4];
#pragma unroll
        for (int p = 0; p < 4; p++)
            outp[p] = (uint_t)f2b(o[2 * p]) | ((uint_t)f2b(o[2 * p + 1]) << 16);
        uint4 ov; ov.x = outp[0]; ov.y = outp[1]; ov.z = outp[2]; ov.w = outp[3];
        *reinterpret_cast<uint4*>(&outb[base]) = ov;
    }
}

extern "C" void kernel_launch(void* const* d_in, const int* in_sizes, int n_in,
                              void* d_out, int out_size, void* d_ws, size_t ws_size,
                              hipStream_t stream) {
    const int*   idx = (const int*)d_in[0];
    const int*   seq = (const int*)d_in[1];
    const float* Wt  = (const float*)d_in[2];
    const float* bt  = (const float*)d_in[3];
    const float* Wa  = (const float*)d_in[4];
    const float* ba  = (const float*)d_in[5];
    const float* Wm  = (const float*)d_in[6];
    const float* bm  = (const float*)d_in[7];
    const float* sos = (const float*)d_in[8];
    const float* Wq  = (const float*)d_in[9];
    const float* bq  = (const float*)d_in[10];
    const float* Wk  = (const float*)d_in[11];
    const float* bk  = (const float*)d_in[12];
    const float* Wv  = (const float*)d_in[13];
    const float* bv  = (const float*)d_in[14];
    const float* Wo  = (const float*)d_in[15];
    const float* bo  = (const float*)d_in[16];
    const float* W1  = (const float*)d_in[17];
    const float* b1  = (const float*)d_in[18];
    const float* W2  = (const float*)d_in[19];
    const float* b2  = (const float*)d_in[20];
    const float* g1  = (const float*)d_in[21];
    const float* be1 = (const float*)d_in[22];
    const float* g2  = (const float*)d_in[23];
    const float* be2 = (const float*)d_in[24];

    const size_t NB = (size_t)L_TOK * DMODEL;

    int* START = (int*)d_ws;
    ushort_t* WB = (ushort_t*)d_ws + 16384;
    ushort_t* WQc = WB + 0 * WELEM;
    ushort_t* WKc = WB + 1 * WELEM;
    ushort_t* WVc = WB + 2 * WELEM;
    ushort_t* WOc = WB + 3 * WELEM;
    ushort_t* W1c = WB + 4 * WELEM;
    ushort_t* W2c = WB + 5 * WELEM;
    ushort_t* bufs = WB + 6 * WELEM;
    ushort_t* B0 = bufs;            // X / attn-out / next-layer X
    ushort_t* B1 = bufs + 1 * NB;   // Q / O-proj out / FF hidden
    ushort_t* B2 = bufs + 2 * NB;   // K / XA
    ushort_t* B3 = bufs + 3 * NB;   // V / FF2 out

    convert_weights<<<1536, 256, 0, stream>>>(Wq, Wk, Wv, Wo, W1, W2, WB);
    embed_kernel<<<6144, 256, 0, stream>>>(idx, Wt, bt, Wa, ba, Wm, bm, sos, B0);
    scan_start<<<1, 1024, 0, stream>>>(seq, START);

    for (int layer = 0; layer < 2; layer++) {
        gemm512<0><<<dim3(48, 8, 3), 256, 0, stream>>>(B0, WQc, WKc, WVc, bq, bk, bv, B1, B2, B3);
        attn_kernel<<<6144, 256, 0, stream>>>(B1, B2, B3, START, B0);
        gemm512<0><<<dim3(48, 8, 1), 256, 0, stream>>>(B0, WOc, WOc, WOc, bo, bo, bo, B1, B1, B1);
        ln_kernel<0, 0><<<768, 256, 0, stream>>>(B1, B1, g1, be1, B2);          // XA -> B2
        gemm512<1><<<dim3(48, 8, 1), 256, 0, stream>>>(B2, W1c, W1c, W1c, b1, b1, b1, B1, B1, B1);
        gemm512<0><<<dim3(48, 8, 1), 256, 0, stream>>>(B1, W2c, W2c, W2c, b2, b2, b2, B3, B3, B3);
        if (layer == 0)
            ln_kernel<1, 0><<<768, 256, 0, stream>>>(B3, B2, g2, be2, B0);      // bf16 internal
        else
            ln_kernel<1, 1><<<768, 256, 0, stream>>>(B3, B2, g2, be2, d_out);   // fp32 final output
    }
}

// Round 5
// 376.944 us; speedup vs baseline: 1.3057x; 1.3057x over previous
//
#include <hip/hip_runtime.h>

typedef unsigned short ushort_t;
typedef unsigned int uint_t;

#define L_TOK 3072
#define DMODEL 512
#define WELEM 262144   // 512*512

using bf16x8 = __attribute__((ext_vector_type(8))) short;
using f32x4  = __attribute__((ext_vector_type(4))) float;

__device__ __forceinline__ float b2f(ushort_t u) {
    union { uint_t i; float f; } c; c.i = ((uint_t)u) << 16; return c.f;
}
__device__ __forceinline__ ushort_t f2b(float f) {
    union { float f; uint_t i; } c; c.f = f;
    uint_t x = c.i;
    return (ushort_t)((x + 0x7fffu + ((x >> 16) & 1u)) >> 16);  // RNE
}

// ---------------- Weight convert: 6 matrices of 512x512 fp32 -> bf16 (RNE)
__global__ __launch_bounds__(256) void convert_weights(
    const float* __restrict__ Wq, const float* __restrict__ Wk, const float* __restrict__ Wv,
    const float* __restrict__ Wo, const float* __restrict__ W1, const float* __restrict__ W2,
    ushort_t* __restrict__ WB)
{
    int gid = blockIdx.x * 256 + threadIdx.x;     // 393216 threads, 4 floats each
    int mat = gid >> 16;
    int off = (gid & 65535) * 4;
    const float* src;
    switch (mat) {
        case 0: src = Wq; break;
        case 1: src = Wk; break;
        case 2: src = Wv; break;
        case 3: src = Wo; break;
        case 4: src = W1; break;
        default: src = W2; break;
    }
    float4 v = *reinterpret_cast<const float4*>(src + off);
    uint2 o;
    o.x = (uint_t)f2b(v.x) | ((uint_t)f2b(v.y) << 16);
    o.y = (uint_t)f2b(v.z) | ((uint_t)f2b(v.w) << 16);
    *reinterpret_cast<uint2*>(&WB[mat * WELEM + off]) = o;
}

// ---------------- Embedding (fp32 tables -> bf16 X)
__global__ __launch_bounds__(256) void embed_kernel(
    const int* __restrict__ idx,
    const float* __restrict__ Wt, const float* __restrict__ bt,
    const float* __restrict__ Wa, const float* __restrict__ ba,
    const float* __restrict__ Wm, const float* __restrict__ bm,
    const float* __restrict__ sos, ushort_t* __restrict__ X)
{
    int gid = blockIdx.x * 256 + threadIdx.x;   // 3072*512 total
    int tok = gid >> 9;
    int d = gid & 511;
    float val;
    if (tok == 0) {
        val = sos[d];
    } else {
        int id = idx[tok - 1];
        int t = id / 219;            // 73*3
        int a = (id / 3) % 73;
        int m = id % 3;
        val = Wt[d * 15 + t] + bt[d]
            + Wa[d * 73 + a] + ba[d]
            + Wm[d * 3 + m] + bm[d];
    }
    X[gid] = f2b(val);
}

// ---------------- start[] scan (ping-pong, race-free)
__global__ __launch_bounds__(1024) void scan_start(const int* __restrict__ seq, int* __restrict__ start)
{
    __shared__ int buf0[1024];
    __shared__ int buf1[1024];
    int tid = threadIdx.x;
    int carry = 0;
    for (int c = 0; c < 3; c++) {
        int i = c * 1024 + tid;
        int b;
        if (i <= 1) b = i;
        else b = (seq[i - 1] == 0) ? i : 0;
        buf0[tid] = b;
        __syncthreads();
        int* src = buf0;
        int* dst = buf1;
        for (int off = 1; off < 1024; off <<= 1) {
            int v = src[tid];
            if (tid >= off) { int u = src[tid - off]; if (u > v) v = u; }
            dst[tid] = v;
            __syncthreads();
            int* t = src; src = dst; dst = t;
        }
        int val = src[tid] > carry ? src[tid] : carry;
        start[i] = val;
        int tot = src[1023] > carry ? src[1023] : carry;
        __syncthreads();
        carry = tot;
    }
}

// ---------------- GEMM: C[3072,512] = A@W^T + bias; A,W,C bf16, bias fp32, fp32 acc
template<int RELU>
__global__ __launch_bounds__(256) void gemm512(
    const ushort_t* __restrict__ A,
    const ushort_t* __restrict__ Wp0, const ushort_t* __restrict__ Wp1, const ushort_t* __restrict__ Wp2,
    const float* __restrict__ bp0, const float* __restrict__ bp1, const float* __restrict__ bp2,
    ushort_t* __restrict__ Cp0, ushort_t* __restrict__ Cp1, ushort_t* __restrict__ Cp2)
{
    const ushort_t* W = Wp0; const float* bias = bp0; ushort_t* C = Cp0;
    if (blockIdx.z == 1) { W = Wp1; bias = bp1; C = Cp1; }
    else if (blockIdx.z == 2) { W = Wp2; bias = bp2; C = Cp2; }

    __shared__ ushort_t As[64 * 72];
    __shared__ ushort_t Bs[64 * 72];

    const int tid = threadIdx.x;
    const int lane = tid & 63;
    const int w = tid >> 6;
    const int lm = lane & 15;
    const int q4 = lane >> 4;

    const int m0 = blockIdx.x * 64;
    const int n0 = blockIdx.y * 64;

    f32x4 acc[4];
#pragma unroll
    for (int i = 0; i < 4; i++) acc[i] = (f32x4){0.f, 0.f, 0.f, 0.f};

    for (int k0 = 0; k0 < 512; k0 += 64) {
        for (int c = tid; c < 512; c += 256) {
            int row = c >> 3, col = (c & 7) << 3;
            uint4 va = *reinterpret_cast<const uint4*>(&A[(size_t)(m0 + row) * 512 + k0 + col]);
            *reinterpret_cast<uint4*>(&As[row * 72 + col]) = va;
            uint4 vb = *reinterpret_cast<const uint4*>(&W[(size_t)(n0 + row) * 512 + k0 + col]);
            *reinterpret_cast<uint4*>(&Bs[row * 72 + col]) = vb;
        }
        __syncthreads();
#pragma unroll
        for (int kk = 0; kk < 64; kk += 32) {
            bf16x8 af = *reinterpret_cast<const bf16x8*>(&As[(w * 16 + lm) * 72 + kk + q4 * 8]);
#pragma unroll
            for (int nt = 0; nt < 4; nt++) {
                bf16x8 bf = *reinterpret_cast<const bf16x8*>(&Bs[(nt * 16 + lm) * 72 + kk + q4 * 8]);
                acc[nt] = __builtin_amdgcn_mfma_f32_16x16x32_bf16(af, bf, acc[nt], 0, 0, 0);
            }
        }
        __syncthreads();
    }

#pragma unroll
    for (int nt = 0; nt < 4; nt++) {
        int col = n0 + nt * 16 + lm;
        float bv = bias[col];
#pragma unroll
        for (int r = 0; r < 4; r++) {
            int row = m0 + w * 16 + q4 * 4 + r;
            float v = acc[nt][r] + bv;
            if (RELU) v = (v > 0.f) ? v : 0.01f * v;
            C[(size_t)row * 512 + col] = f2b(v);
        }
    }
}

// ---------------- Sparse attention: keys = {0} ∪ [start[i], i-1], one wave per (token i, head h)
// PV restructured: V rows staged to per-wave LDS tile, p to LDS, fixed-64 unrolled
// parallel-over-keys accumulation (breaks the serial load-latency chain of the old loop).
__global__ __launch_bounds__(256) void attn_kernel(
    const ushort_t* __restrict__ Q, const ushort_t* __restrict__ K,
    const ushort_t* __restrict__ V, const int* __restrict__ START,
    ushort_t* __restrict__ O)
{
    __shared__ ushort_t Vs[4][64 * 66];   // pad 66: PV-read banks rotate per key row -> conflict-free
    __shared__ float ps[4][64];

    int w = threadIdx.x >> 6;
    int lane = threadIdx.x & 63;
    int wid = blockIdx.x * 4 + w;
    int i = wid >> 3;
    int h = wid & 7;

    float qv = b2f(Q[(size_t)i * 512 + h * 64 + lane]) * 0.125f;  // fold 1/sqrt(64)
    int si = START[i];
    if (si < 1) si = 1;
    if (si > i) si = i;
    int nk = (i == 0) ? 1 : (i - si + 1);

    float m_run = -INFINITY, l_run = 0.f, o_acc = 0.f;

    for (int t0 = 0; t0 < nk; t0 += 64) {
        int t = t0 + lane;
        bool valid = t < nk;
        int j = (t == 0) ? 0 : (si + t - 1);
        if (!valid) j = 0;
        if (j < 0) j = 0; if (j > L_TOK - 1) j = L_TOK - 1;

        // Issue K-row and V-row loads together (8+8 independent 16B loads in flight per lane)
        const uint4* kp = reinterpret_cast<const uint4*>(&K[(size_t)j * 512 + h * 64]);
        const uint4* vp = reinterpret_cast<const uint4*>(&V[(size_t)j * 512 + h * 64]);
        uint4 kr[8];
        uint4 vr[8];
#pragma unroll
        for (int c = 0; c < 8; c++) kr[c] = kp[c];
#pragma unroll
        for (int c = 0; c < 8; c++) vr[c] = vp[c];

        // QK dot product: lane j owns key j; q broadcast via shfl
        float s = 0.f;
#pragma unroll
        for (int c = 0; c < 8; c++) {
            uint_t uu[4] = {kr[c].x, kr[c].y, kr[c].z, kr[c].w};
#pragma unroll
            for (int p2 = 0; p2 < 4; p2++) {
                int d = c * 8 + p2 * 2;
                s += __shfl(qv, d) * b2f((ushort_t)(uu[p2] & 0xffffu));
                s += __shfl(qv, d + 1) * b2f((ushort_t)(uu[p2] >> 16));
            }
        }
        if (!valid) s = -INFINITY;

        // Stash V row to LDS (packed bf16), per-wave private tile
#pragma unroll
        for (int c = 0; c < 8; c++)
            *reinterpret_cast<uint4*>(&Vs[w][lane * 66 + c * 8]) = vr[c];

        // Online softmax
        float tmax = s;
#pragma unroll
        for (int off = 32; off > 0; off >>= 1) tmax = fmaxf(tmax, __shfl_xor(tmax, off));
        float m_new = fmaxf(m_run, tmax);
        float p = valid ? __expf(s - m_new) : 0.f;
        float psum = p;
#pragma unroll
        for (int off = 32; off > 0; off >>= 1) psum += __shfl_xor(psum, off);
        float alpha = (m_run == -INFINITY) ? 0.f : __expf(m_run - m_new);
        l_run = l_run * alpha + psum;
        o_acc *= alpha;

        ps[w][lane] = p;    // invalid lanes hold 0 -> full-64 PV loop needs no bound

        // PV: o[lane] += sum_j p_j * V[j][lane]; broadcast ps read + conflict-free Vs read,
        // fixed trip count -> fully unrolled, ds_reads pipeline at throughput.
#pragma unroll
        for (int j2 = 0; j2 < 64; j2++) {
            float pj = ps[w][j2];
            o_acc += pj * b2f(Vs[w][j2 * 66 + lane]);
        }
        m_run = m_new;
    }
    float inv = (l_run > 0.f) ? (1.f / l_run) : 0.f;
    O[(size_t)i * 512 + h * 64 + lane] = f2b(o_acc * inv);
}

// ---------------- LayerNorm (one wave per token); RESID adds R; F32OUT selects output format
template<int RESID, int F32OUT>
__global__ __launch_bounds__(256) void ln_kernel(
    const ushort_t* __restrict__ X, const ushort_t* __restrict__ R,
    const float* __restrict__ g, const float* __restrict__ be,
    void* __restrict__ outv)
{
    int tok = blockIdx.x * 4 + (threadIdx.x >> 6);
    int lane = threadIdx.x & 63;
    size_t base = (size_t)tok * 512 + lane * 8;

    float v[8];
    {
        uint4 ux = *reinterpret_cast<const uint4*>(&X[base]);
        uint_t ua[4] = {ux.x, ux.y, ux.z, ux.w};
#pragma unroll
        for (int p = 0; p < 4; p++) {
            v[2 * p] = b2f((ushort_t)(ua[p] & 0xffffu));
            v[2 * p + 1] = b2f((ushort_t)(ua[p] >> 16));
        }
        if (RESID) {
            uint4 ur = *reinterpret_cast<const uint4*>(&R[base]);
            uint_t ub[4] = {ur.x, ur.y, ur.z, ur.w};
#pragma unroll
            for (int p = 0; p < 4; p++) {
                v[2 * p] += b2f((ushort_t)(ub[p] & 0xffffu));
                v[2 * p + 1] += b2f((ushort_t)(ub[p] >> 16));
            }
        }
    }
    float sum = 0.f;
#pragma unroll
    for (int j = 0; j < 8; j++) sum += v[j];
#pragma unroll
    for (int off = 32; off > 0; off >>= 1) sum += __shfl_xor(sum, off);
    float mu = sum * (1.f / 512.f);
    float var = 0.f;
#pragma unroll
    for (int j = 0; j < 8; j++) { float d = v[j] - mu; var += d * d; }
#pragma unroll
    for (int off = 32; off > 0; off >>= 1) var += __shfl_xor(var, off);
    float rstd = rsqrtf(var * (1.f / 512.f) + 1e-5f);

    const float4* gp = reinterpret_cast<const float4*>(g);
    const float4* bp = reinterpret_cast<const float4*>(be);
    float4 g0 = gp[2 * lane], g1 = gp[2 * lane + 1];
    float4 b0 = bp[2 * lane], b1 = bp[2 * lane + 1];
    float gg[8] = {g0.x, g0.y, g0.z, g0.w, g1.x, g1.y, g1.z, g1.w};
    float bb[8] = {b0.x, b0.y, b0.z, b0.w, b1.x, b1.y, b1.z, b1.w};

    float o[8];
#pragma unroll
    for (int j = 0; j < 8; j++) o[j] = (v[j] - mu) * rstd * gg[j] + bb[j];

    if (F32OUT) {
        float* outf = (float*)outv;
        float4 o0 = {o[0], o[1], o[2], o[3]};
        float4 o1 = {o[4], o[5], o[6], o[7]};
        *reinterpret_cast<float4*>(&outf[base]) = o0;
        *reinterpret_cast<float4*>(&outf[base + 4]) = o1;
    } else {
        ushort_t* outb = (ushort_t*)outv;
        uint_t outp[4];
#pragma unroll
        for (int p = 0; p < 4; p++)
            outp[p] = (uint_t)f2b(o[2 * p]) | ((uint_t)f2b(o[2 * p + 1]) << 16);
        uint4 ov; ov.x = outp[0]; ov.y = outp[1]; ov.z = outp[2]; ov.w = outp[3];
        *reinterpret_cast<uint4*>(&outb[base]) = ov;
    }
}

extern "C" void kernel_launch(void* const* d_in, const int* in_sizes, int n_in,
                              void* d_out, int out_size, void* d_ws, size_t ws_size,
                              hipStream_t stream) {
    const int*   idx = (const int*)d_in[0];
    const int*   seq = (const int*)d_in[1];
    const float* Wt  = (const float*)d_in[2];
    const float* bt  = (const float*)d_in[3];
    const float* Wa  = (const float*)d_in[4];
    const float* ba  = (const float*)d_in[5];
    const float* Wm  = (const float*)d_in[6];
    const float* bm  = (const float*)d_in[7];
    const float* sos = (const float*)d_in[8];
    const float* Wq  = (const float*)d_in[9];
    const float* bq  = (const float*)d_in[10];
    const float* Wk  = (const float*)d_in[11];
    const float* bk  = (const float*)d_in[12];
    const float* Wv  = (const float*)d_in[13];
    const float* bv  = (const float*)d_in[14];
    const float* Wo  = (const float*)d_in[15];
    const float* bo  = (const float*)d_in[16];
    const float* W1  = (const float*)d_in[17];
    const float* b1  = (const float*)d_in[18];
    const float* W2  = (const float*)d_in[19];
    const float* b2  = (const float*)d_in[20];
    const float* g1  = (const float*)d_in[21];
    const float* be1 = (const float*)d_in[22];
    const float* g2  = (const float*)d_in[23];
    const float* be2 = (const float*)d_in[24];

    const size_t NB = (size_t)L_TOK * DMODEL;

    int* START = (int*)d_ws;
    ushort_t* WB = (ushort_t*)d_ws + 16384;
    ushort_t* WQc = WB + 0 * WELEM;
    ushort_t* WKc = WB + 1 * WELEM;
    ushort_t* WVc = WB + 2 * WELEM;
    ushort_t* WOc = WB + 3 * WELEM;
    ushort_t* W1c = WB + 4 * WELEM;
    ushort_t* W2c = WB + 5 * WELEM;
    ushort_t* bufs = WB + 6 * WELEM;
    ushort_t* B0 = bufs;            // X / attn-out / next-layer X
    ushort_t* B1 = bufs + 1 * NB;   // Q / O-proj out / FF hidden
    ushort_t* B2 = bufs + 2 * NB;   // K / XA
    ushort_t* B3 = bufs + 3 * NB;   // V / FF2 out

    convert_weights<<<1536, 256, 0, stream>>>(Wq, Wk, Wv, Wo, W1, W2, WB);
    embed_kernel<<<6144, 256, 0, stream>>>(idx, Wt, bt, Wa, ba, Wm, bm, sos, B0);
    scan_start<<<1, 1024, 0, stream>>>(seq, START);

    for (int layer = 0; layer < 2; layer++) {
        gemm512<0><<<dim3(48, 8, 3), 256, 0, stream>>>(B0, WQc, WKc, WVc, bq, bk, bv, B1, B2, B3);
        attn_kernel<<<6144, 256, 0, stream>>>(B1, B2, B3, START, B0);
        gemm512<0><<<dim3(48, 8, 1), 256, 0, stream>>>(B0, WOc, WOc, WOc, bo, bo, bo, B1, B1, B1);
        ln_kernel<0, 0><<<768, 256, 0, stream>>>(B1, B1, g1, be1, B2);          // XA -> B2
        gemm512<1><<<dim3(48, 8, 1), 256, 0, stream>>>(B2, W1c, W1c, W1c, b1, b1, b1, B1, B1, B1);
        gemm512<0><<<dim3(48, 8, 1), 256, 0, stream>>>(B1, W2c, W2c, W2c, b2, b2, b2, B3, B3, B3);
        if (layer == 0)
            ln_kernel<1, 0><<<768, 256, 0, stream>>>(B3, B2, g2, be2, B0);      // bf16 internal
        else
            ln_kernel<1, 1><<<768, 256, 0, stream>>>(B3, B2, g2, be2, d_out);   // fp32 final output
    }
}